// Round 1
// baseline (150.730 us; speedup 1.0000x reference)
//
#include <hip/hip_runtime.h>
#include <math.h>

// Problem shape (fixed by reference setup_inputs)
constexpr int B = 64;
constexpr int C = 13;
constexpr int HW = 128 * 128;               // 16384
constexpr long long NTOT = (long long)B * C * HW;   // 13,631,488
constexpr long long NSAMP = (long long)B * HW;      // 1,048,576

// Output layout (concatenated flat, all read back as float32)
constexpr long long COMMIT_OFF = NTOT;
constexpr long long ENT_OFF = NTOT + 1;
constexpr long long IDX_OFF = NTOT + 2;

constexpr int THREADS = 256;
constexpr int VEC = 4;
constexpr int CHUNK = THREADS * VEC;        // 1024 hw positions per block
constexpr int BLOCKS_PER_B = HW / CHUNK;    // 16
constexpr int NACC = 15;                    // [0]=commit, [1]=entropy, [2..14]=p0 per channel

__global__ __launch_bounds__(THREADS) void lfq_main(const float* __restrict__ z,
                                                    float* __restrict__ out,
                                                    double* __restrict__ acc) {
    const int bid = blockIdx.x;
    const int b = bid / BLOCKS_PER_B;
    const int j = bid % BLOCKS_PER_B;
    const int hw0 = j * CHUNK + (int)threadIdx.x * VEC;

    float cm_s = 0.0f;
    float ent_s = 0.0f;
    float p0_s[C];
#pragma unroll
    for (int c = 0; c < C; ++c) p0_s[c] = 0.0f;
    int idx[VEC] = {0, 0, 0, 0};

    const float* zb = z + (size_t)b * C * HW + hw0;
    float* zq = out + (size_t)b * C * HW + hw0;

#pragma unroll
    for (int c = 0; c < C; ++c) {
        const float4 v = *reinterpret_cast<const float4*>(zb + (size_t)c * HW);
        float zz[VEC] = {v.x, v.y, v.z, v.w};
        float qq[VEC];
#pragma unroll
        for (int k = 0; k < VEC; ++k) {
            const float zv = zz[k];
            const bool pos = (zv > 0.0f);
            const float q = pos ? 1.0f : -1.0f;
            qq[k] = q;
            const float d = q - zv;
            cm_s += d * d;
            // binary entropy of p0 = sigmoid(4z), stable via softplus
            const float t = 4.0f * zv;
            const float ax = fabsf(t);
            const float e = expf(-ax);             // in (0,1]
            const float sp_pos = log1pf(e);        // softplus(-|t|) = -log p_big
            const float sp_neg = ax + sp_pos;      // softplus(+|t|) = -log p_small
            const float inv = 1.0f / (1.0f + e);
            const float p_big = inv;               // sigmoid(|t|)
            const float p_small = e * inv;         // sigmoid(-|t|)
            ent_s += p_big * sp_pos + p_small * sp_neg;
            p0_s[c] += (t >= 0.0f) ? p_big : p_small;  // p0 = sigmoid(t)
            if (pos) idx[k] |= (1 << (C - 1 - c));     // MSB = channel 0
        }
        float4 qv;
        qv.x = qq[0]; qv.y = qq[1]; qv.z = qq[2]; qv.w = qq[3];
        *reinterpret_cast<float4*>(zq + (size_t)c * HW) = qv;
    }

    // bit-packed indices, stored as float values (exact up to 8191)
    float4 fi;
    fi.x = (float)idx[0]; fi.y = (float)idx[1]; fi.z = (float)idx[2]; fi.w = (float)idx[3];
    *reinterpret_cast<float4*>(out + IDX_OFF + (size_t)b * HW + hw0) = fi;

    // block reduction of 15 partials
    float vals[NACC];
    vals[0] = cm_s;
    vals[1] = ent_s;
#pragma unroll
    for (int c = 0; c < C; ++c) vals[2 + c] = p0_s[c];
#pragma unroll
    for (int off = 32; off > 0; off >>= 1) {
#pragma unroll
        for (int k = 0; k < NACC; ++k) vals[k] += __shfl_down(vals[k], off);
    }
    __shared__ float red[THREADS / 64][NACC];
    const int wave = threadIdx.x >> 6;
    const int lane = threadIdx.x & 63;
    if (lane == 0) {
#pragma unroll
        for (int k = 0; k < NACC; ++k) red[wave][k] = vals[k];
    }
    __syncthreads();
    if (threadIdx.x < NACC) {
        double s = 0.0;
#pragma unroll
        for (int w = 0; w < THREADS / 64; ++w) s += (double)red[w][threadIdx.x];
        atomicAdd(&acc[threadIdx.x], s);
    }
}

__global__ void lfq_final(const double* __restrict__ acc, float* __restrict__ out) {
    if (threadIdx.x == 0 && blockIdx.x == 0) {
        const double commit = acc[0] / (double)NTOT;
        const double ent = acc[1] / (double)NTOT;
        double me = 0.0;
        for (int c = 0; c < C; ++c) {
            const double mp0 = acc[2 + c] / (double)NSAMP;
            const double mp1 = 1.0 - mp0;
            me += -(mp0 * log(mp0) + mp1 * log(mp1));
        }
        me /= (double)C;
        out[COMMIT_OFF] = (float)(0.1 * 1.25 * commit);  // COMMIT_MULT * (1 + BETA)
        out[ENT_OFF] = (float)(0.1 * (ent - me));        // ENT_MULT
    }
}

extern "C" void kernel_launch(void* const* d_in, const int* in_sizes, int n_in,
                              void* d_out, int out_size, void* d_ws, size_t ws_size,
                              hipStream_t stream) {
    const float* z = (const float*)d_in[0];
    float* out = (float*)d_out;
    double* acc = (double*)d_ws;

    // workspace is poisoned 0xAA before every launch — zero the accumulators
    hipMemsetAsync(d_ws, 0, NACC * sizeof(double), stream);
    lfq_main<<<B * BLOCKS_PER_B, THREADS, 0, stream>>>(z, out, acc);
    lfq_final<<<1, 64, 0, stream>>>(acc, out);
}

// Round 2
// 128.109 us; speedup vs baseline: 1.1766x; 1.1766x over previous
//
#include <hip/hip_runtime.h>
#include <math.h>

// Problem shape (fixed by reference setup_inputs)
constexpr int B = 64;
constexpr int C = 13;
constexpr int HW = 128 * 128;               // 16384
constexpr long long NTOT = (long long)B * C * HW;   // 13,631,488
constexpr long long NSAMP = (long long)B * HW;      // 1,048,576

// Output layout (concatenated flat, all read back as float32)
constexpr long long COMMIT_OFF = NTOT;
constexpr long long ENT_OFF = NTOT + 1;
constexpr long long IDX_OFF = NTOT + 2;

constexpr int THREADS = 256;
constexpr int VEC = 2;
constexpr int CHUNK = THREADS * VEC;        // 512 hw positions per block
constexpr int BLOCKS_PER_B = HW / CHUNK;    // 32
constexpr int NACC = 15;                    // [0]=commit, [1]=entropy, [2..14]=p0 per channel

__global__ __launch_bounds__(THREADS, 8) void lfq_main(const float* __restrict__ z,
                                                       float* __restrict__ out,
                                                       double* __restrict__ acc) {
    constexpr float kLog2e4 = 5.7707801635558535f;  // 4*log2(e)
    constexpr float kLn2 = 0.6931471805599453f;

    const int bid = blockIdx.x;
    const int b = bid / BLOCKS_PER_B;
    const int j = bid % BLOCKS_PER_B;
    const int hw0 = j * CHUNK + (int)threadIdx.x * VEC;

    float cm_s = 0.0f;
    float ent_s = 0.0f;
    float p0_s[C];
#pragma unroll
    for (int c = 0; c < C; ++c) p0_s[c] = 0.0f;
    int idx[VEC] = {0, 0};

    const float* zb = z + (size_t)b * C * HW + hw0;
    float* zq = out + (size_t)b * C * HW + hw0;

#pragma unroll
    for (int c = 0; c < C; ++c) {
        const float2 v = *reinterpret_cast<const float2*>(zb + (size_t)c * HW);
        float zz[VEC] = {v.x, v.y};
        float qq[VEC];
#pragma unroll
        for (int k = 0; k < VEC; ++k) {
            const float zv = zz[k];
            const bool pos = (zv > 0.0f);
            qq[k] = pos ? 1.0f : -1.0f;
            const float az = fabsf(zv);
            // (q - z)^2 == (|z| - 1)^2 since q = sign(z)
            const float dm = az - 1.0f;
            cm_s = fmaf(dm, dm, cm_s);
            // binary entropy of p = sigmoid(4z):
            //   H = log1p(e) + 4|z| * sigmoid(-4|z|),  e = exp(-4|z|)
            const float e = __builtin_amdgcn_exp2f(-kLog2e4 * az);   // v_exp_f32
            const float ope = 1.0f + e;
            const float sp = __builtin_amdgcn_logf(ope) * kLn2;      // v_log_f32
            const float ps = e * __builtin_amdgcn_rcpf(ope);         // sigmoid(-4|z|)
            ent_s += fmaf(4.0f * az, ps, sp);
            p0_s[c] += pos ? (1.0f - ps) : ps;                       // p0 = sigmoid(4z)
            if (pos) idx[k] |= (1 << (C - 1 - c));                   // MSB = channel 0
        }
        float2 qv;
        qv.x = qq[0]; qv.y = qq[1];
        *reinterpret_cast<float2*>(zq + (size_t)c * HW) = qv;
    }

    // bit-packed indices, stored as float values (exact up to 8191)
    float2 fi;
    fi.x = (float)idx[0]; fi.y = (float)idx[1];
    *reinterpret_cast<float2*>(out + IDX_OFF + (size_t)b * HW + hw0) = fi;

    // block reduction of 15 partials
    float vals[NACC];
    vals[0] = cm_s;
    vals[1] = ent_s;
#pragma unroll
    for (int c = 0; c < C; ++c) vals[2 + c] = p0_s[c];
#pragma unroll
    for (int off = 32; off > 0; off >>= 1) {
#pragma unroll
        for (int k = 0; k < NACC; ++k) vals[k] += __shfl_down(vals[k], off);
    }
    __shared__ float red[THREADS / 64][NACC];
    const int wave = threadIdx.x >> 6;
    const int lane = threadIdx.x & 63;
    if (lane == 0) {
#pragma unroll
        for (int k = 0; k < NACC; ++k) red[wave][k] = vals[k];
    }
    __syncthreads();
    if (threadIdx.x < NACC) {
        double s = 0.0;
#pragma unroll
        for (int w = 0; w < THREADS / 64; ++w) s += (double)red[w][threadIdx.x];
        atomicAdd(&acc[threadIdx.x], s);
    }
}

__global__ void lfq_final(const double* __restrict__ acc, float* __restrict__ out) {
    if (threadIdx.x == 0 && blockIdx.x == 0) {
        const double commit = acc[0] / (double)NTOT;
        const double ent = acc[1] / (double)NTOT;
        double me = 0.0;
        for (int c = 0; c < C; ++c) {
            const double mp0 = acc[2 + c] / (double)NSAMP;
            const double mp1 = 1.0 - mp0;
            me += -(mp0 * log(mp0) + mp1 * log(mp1));
        }
        me /= (double)C;
        out[COMMIT_OFF] = (float)(0.1 * 1.25 * commit);  // COMMIT_MULT * (1 + BETA)
        out[ENT_OFF] = (float)(0.1 * (ent - me));        // ENT_MULT
    }
}

extern "C" void kernel_launch(void* const* d_in, const int* in_sizes, int n_in,
                              void* d_out, int out_size, void* d_ws, size_t ws_size,
                              hipStream_t stream) {
    const float* z = (const float*)d_in[0];
    float* out = (float*)d_out;
    double* acc = (double*)d_ws;

    // workspace is poisoned 0xAA before every launch — zero the accumulators
    hipMemsetAsync(d_ws, 0, NACC * sizeof(double), stream);
    lfq_main<<<B * BLOCKS_PER_B, THREADS, 0, stream>>>(z, out, acc);
    lfq_final<<<1, 64, 0, stream>>>(acc, out);
}

// Round 3
// 115.271 us; speedup vs baseline: 1.3076x; 1.1114x over previous
//
#include <hip/hip_runtime.h>
#include <math.h>

// Problem shape (fixed by reference setup_inputs)
constexpr int B = 64;
constexpr int C = 13;
constexpr int HW = 128 * 128;               // 16384
constexpr long long NTOT = (long long)B * C * HW;   // 13,631,488
constexpr long long NSAMP = (long long)B * HW;      // 1,048,576

// Output layout (concatenated flat, all read back as float32)
constexpr long long COMMIT_OFF = NTOT;
constexpr long long ENT_OFF = NTOT + 1;
constexpr long long IDX_OFF = NTOT + 2;

constexpr int THREADS = 256;
constexpr int VEC = 4;
constexpr int CHUNK = THREADS * VEC;        // 1024 hw positions per block
constexpr int BLOCKS_PER_B = HW / CHUNK;    // 16
constexpr int NBLK = B * BLOCKS_PER_B;      // 1024 blocks
constexpr int NACC = 15;                    // [0]=commit, [1]=entropy, [2..14]=p0 per channel
constexpr int SLOT = 16;                    // padded stride for per-block partials in d_ws

__global__ __launch_bounds__(THREADS, 4) void lfq_main(const float* __restrict__ z,
                                                       float* __restrict__ out,
                                                       float* __restrict__ part) {
    constexpr float kLog2e4 = 5.7707801635558535f;  // 4*log2(e)
    constexpr float kLn2 = 0.6931471805599453f;

    const int bid = blockIdx.x;
    const int b = bid / BLOCKS_PER_B;
    const int j = bid % BLOCKS_PER_B;
    const int hw0 = j * CHUNK + (int)threadIdx.x * VEC;

    float cm_s = 0.0f;
    float ent_s = 0.0f;
    float p0_s[C];
#pragma unroll
    for (int c = 0; c < C; ++c) p0_s[c] = 0.0f;
    int idx[VEC] = {0, 0, 0, 0};

    const float* zb = z + (size_t)b * C * HW + hw0;
    float* zq = out + (size_t)b * C * HW + hw0;

#pragma unroll
    for (int c = 0; c < C; ++c) {
        const float4 v = *reinterpret_cast<const float4*>(zb + (size_t)c * HW);
        float zz[VEC] = {v.x, v.y, v.z, v.w};
        float qq[VEC];
#pragma unroll
        for (int k = 0; k < VEC; ++k) {
            const float zv = zz[k];
            const bool pos = (zv > 0.0f);
            qq[k] = pos ? 1.0f : -1.0f;
            const float az = fabsf(zv);
            // (q - z)^2 == (|z| - 1)^2 since q = sign(z)
            const float dm = az - 1.0f;
            cm_s = fmaf(dm, dm, cm_s);
            // binary entropy of p = sigmoid(4z):
            //   H = log1p(e) + 4|z| * sigmoid(-4|z|),  e = exp(-4|z|)
            const float e = __builtin_amdgcn_exp2f(-kLog2e4 * az);   // v_exp_f32
            const float ope = 1.0f + e;
            const float sp = __builtin_amdgcn_logf(ope) * kLn2;      // v_log_f32
            const float ps = e * __builtin_amdgcn_rcpf(ope);         // sigmoid(-4|z|)
            ent_s += fmaf(4.0f * az, ps, sp);
            p0_s[c] += pos ? (1.0f - ps) : ps;                       // p0 = sigmoid(4z)
            if (pos) idx[k] |= (1 << (C - 1 - c));                   // MSB = channel 0
        }
        float4 qv;
        qv.x = qq[0]; qv.y = qq[1]; qv.z = qq[2]; qv.w = qq[3];
        *reinterpret_cast<float4*>(zq + (size_t)c * HW) = qv;
    }

    // bit-packed indices, stored as float values (exact up to 8191)
    float4 fi;
    fi.x = (float)idx[0]; fi.y = (float)idx[1]; fi.z = (float)idx[2]; fi.w = (float)idx[3];
    *reinterpret_cast<float4*>(out + IDX_OFF + (size_t)b * HW + hw0) = fi;

    // block reduction of 15 partials -> per-block slot in workspace (no atomics)
    float vals[NACC];
    vals[0] = cm_s;
    vals[1] = ent_s;
#pragma unroll
    for (int c = 0; c < C; ++c) vals[2 + c] = p0_s[c];
#pragma unroll
    for (int off = 32; off > 0; off >>= 1) {
#pragma unroll
        for (int k = 0; k < NACC; ++k) vals[k] += __shfl_down(vals[k], off);
    }
    __shared__ float red[THREADS / 64][NACC];
    const int wave = threadIdx.x >> 6;
    const int lane = threadIdx.x & 63;
    if (lane == 0) {
#pragma unroll
        for (int k = 0; k < NACC; ++k) red[wave][k] = vals[k];
    }
    __syncthreads();
    if (threadIdx.x < NACC) {
        float s = 0.0f;
#pragma unroll
        for (int w = 0; w < THREADS / 64; ++w) s += red[w][threadIdx.x];
        part[(size_t)bid * SLOT + threadIdx.x] = s;
    }
}

// One block, one thread per lfq_main block; reduces 1024 x 15 partials.
__global__ __launch_bounds__(NBLK) void lfq_final(const float* __restrict__ part,
                                                  float* __restrict__ out) {
    const int t = threadIdx.x;  // 0..1023
    float vals[NACC];
    const float* p = part + (size_t)t * SLOT;
#pragma unroll
    for (int k = 0; k < NACC; ++k) vals[k] = p[k];
#pragma unroll
    for (int off = 32; off > 0; off >>= 1) {
#pragma unroll
        for (int k = 0; k < NACC; ++k) vals[k] += __shfl_down(vals[k], off);
    }
    __shared__ float red[NBLK / 64][NACC];
    const int wave = t >> 6;
    const int lane = t & 63;
    if (lane == 0) {
#pragma unroll
        for (int k = 0; k < NACC; ++k) red[wave][k] = vals[k];
    }
    __syncthreads();
    if (t == 0) {
        double acc[NACC];
#pragma unroll
        for (int k = 0; k < NACC; ++k) {
            double s = 0.0;
#pragma unroll
            for (int w = 0; w < NBLK / 64; ++w) s += (double)red[w][k];
            acc[k] = s;
        }
        const double commit = acc[0] / (double)NTOT;
        const double ent = acc[1] / (double)NTOT;
        double me = 0.0;
        for (int c = 0; c < C; ++c) {
            const double mp0 = acc[2 + c] / (double)NSAMP;
            const double mp1 = 1.0 - mp0;
            me += -(mp0 * log(mp0) + mp1 * log(mp1));
        }
        me /= (double)C;
        out[COMMIT_OFF] = (float)(0.1 * 1.25 * commit);  // COMMIT_MULT * (1 + BETA)
        out[ENT_OFF] = (float)(0.1 * (ent - me));        // ENT_MULT
    }
}

extern "C" void kernel_launch(void* const* d_in, const int* in_sizes, int n_in,
                              void* d_out, int out_size, void* d_ws, size_t ws_size,
                              hipStream_t stream) {
    const float* z = (const float*)d_in[0];
    float* out = (float*)d_out;
    float* part = (float*)d_ws;

    lfq_main<<<NBLK, THREADS, 0, stream>>>(z, out, part);
    lfq_final<<<1, NBLK, 0, stream>>>(part, out);
}

// Round 5
// 111.388 us; speedup vs baseline: 1.3532x; 1.0349x over previous
//
#include <hip/hip_runtime.h>
#include <math.h>

// Problem shape (fixed by reference setup_inputs)
constexpr int B = 64;
constexpr int C = 13;
constexpr int HW = 128 * 128;               // 16384
constexpr long long NTOT = (long long)B * C * HW;   // 13,631,488
constexpr long long NSAMP = (long long)B * HW;      // 1,048,576

// Output layout (concatenated flat, all read back as float32)
constexpr long long COMMIT_OFF = NTOT;
constexpr long long ENT_OFF = NTOT + 1;
constexpr long long IDX_OFF = NTOT + 2;

constexpr int THREADS = 256;
constexpr int VEC = 4;
constexpr int CHUNK = THREADS * VEC;        // 1024 hw positions per block
constexpr int BLOCKS_PER_B = HW / CHUNK;    // 16
constexpr int NBLK = B * BLOCKS_PER_B;      // 1024 blocks
constexpr int NACC = 15;                    // [0]=commit, [1]=entropy, [2..14]=p0 per channel
constexpr int SLOT = 16;                    // padded stride for per-block partials in d_ws

// native clang vector type — required by __builtin_nontemporal_store
typedef float nfloat4 __attribute__((ext_vector_type(4)));

__global__ __launch_bounds__(THREADS, 4) void lfq_main(const float* __restrict__ z,
                                                       float* __restrict__ out,
                                                       float* __restrict__ part) {
    constexpr float kLog2e4 = 5.7707801635558535f;  // 4*log2(e)
    constexpr float kLn2 = 0.6931471805599453f;

    const int bid = blockIdx.x;
    const int b = bid / BLOCKS_PER_B;
    const int j = bid % BLOCKS_PER_B;
    const int hw0 = j * CHUNK + (int)threadIdx.x * VEC;

    float cm_s = 0.0f;
    float ent_s = 0.0f;
    float p0_s[C];
#pragma unroll
    for (int c = 0; c < C; ++c) p0_s[c] = 0.0f;
    int idx[VEC] = {0, 0, 0, 0};

    const float* zb = z + (size_t)b * C * HW + hw0;
    float* zq = out + (size_t)b * C * HW + hw0;

#pragma unroll
    for (int c = 0; c < C; ++c) {
        const float4 v = *reinterpret_cast<const float4*>(zb + (size_t)c * HW);
        float zz[VEC] = {v.x, v.y, v.z, v.w};
        float qq[VEC];
#pragma unroll
        for (int k = 0; k < VEC; ++k) {
            const float zv = zz[k];
            const bool pos = (zv > 0.0f);
            qq[k] = pos ? 1.0f : -1.0f;
            const float az = fabsf(zv);
            // (q - z)^2 == (|z| - 1)^2 since q = sign(z)
            const float dm = az - 1.0f;
            cm_s = fmaf(dm, dm, cm_s);
            // binary entropy of p = sigmoid(4z):
            //   H = log1p(e) + 4|z| * sigmoid(-4|z|),  e = exp(-4|z|)
            const float e = __builtin_amdgcn_exp2f(-kLog2e4 * az);   // v_exp_f32
            const float ope = 1.0f + e;
            const float sp = __builtin_amdgcn_logf(ope) * kLn2;      // v_log_f32
            const float ps = e * __builtin_amdgcn_rcpf(ope);         // sigmoid(-4|z|)
            ent_s += fmaf(4.0f * az, ps, sp);
            p0_s[c] += pos ? (1.0f - ps) : ps;                       // p0 = sigmoid(4z)
            if (pos) idx[k] |= (1 << (C - 1 - c));                   // MSB = channel 0
        }
        nfloat4 qv = {qq[0], qq[1], qq[2], qq[3]};
        // non-temporal: stream outputs past L2/L3 so the input stays cache-resident
        __builtin_nontemporal_store(qv, reinterpret_cast<nfloat4*>(zq + (size_t)c * HW));
    }

    // bit-packed indices, stored as float values (exact up to 8191)
    nfloat4 fi = {(float)idx[0], (float)idx[1], (float)idx[2], (float)idx[3]};
    __builtin_nontemporal_store(fi, reinterpret_cast<nfloat4*>(out + IDX_OFF + (size_t)b * HW + hw0));

    // block reduction of 15 partials -> per-block slot in workspace (no atomics)
    float vals[NACC];
    vals[0] = cm_s;
    vals[1] = ent_s;
#pragma unroll
    for (int c = 0; c < C; ++c) vals[2 + c] = p0_s[c];
#pragma unroll
    for (int off = 32; off > 0; off >>= 1) {
#pragma unroll
        for (int k = 0; k < NACC; ++k) vals[k] += __shfl_down(vals[k], off);
    }
    __shared__ float red[THREADS / 64][NACC];
    const int wave = threadIdx.x >> 6;
    const int lane = threadIdx.x & 63;
    if (lane == 0) {
#pragma unroll
        for (int k = 0; k < NACC; ++k) red[wave][k] = vals[k];
    }
    __syncthreads();
    if (threadIdx.x < NACC) {
        float s = 0.0f;
#pragma unroll
        for (int w = 0; w < THREADS / 64; ++w) s += red[w][threadIdx.x];
        part[(size_t)bid * SLOT + threadIdx.x] = s;
    }
}

// One block, one thread per lfq_main block; reduces 1024 x 15 partials.
// Tail parallelized: 13 double logs run SIMT-concurrently instead of serially.
__global__ __launch_bounds__(NBLK) void lfq_final(const float* __restrict__ part,
                                                  float* __restrict__ out) {
    const int t = threadIdx.x;  // 0..1023
    float vals[NACC];
    const float* p = part + (size_t)t * SLOT;
#pragma unroll
    for (int k = 0; k < NACC; ++k) vals[k] = p[k];
#pragma unroll
    for (int off = 32; off > 0; off >>= 1) {
#pragma unroll
        for (int k = 0; k < NACC; ++k) vals[k] += __shfl_down(vals[k], off);
    }
    __shared__ float red[NBLK / 64][NACC];
    const int wave = t >> 6;
    const int lane = t & 63;
    if (lane == 0) {
#pragma unroll
        for (int k = 0; k < NACC; ++k) red[wave][k] = vals[k];
    }
    __syncthreads();
    __shared__ double accs[NACC];
    if (t < NACC) {
        double s = 0.0;
#pragma unroll
        for (int w = 0; w < NBLK / 64; ++w) s += (double)red[w][t];
        accs[t] = s;
    }
    __syncthreads();
    __shared__ double ment[C];
    if (t < C) {
        const double mp0 = accs[2 + t] / (double)NSAMP;
        const double mp1 = 1.0 - mp0;
        ment[t] = -(mp0 * log(mp0) + mp1 * log(mp1));  // 13 lanes, one SIMT log pass
    }
    __syncthreads();
    if (t == 0) {
        double me = 0.0;
#pragma unroll
        for (int c = 0; c < C; ++c) me += ment[c];
        me /= (double)C;
        const double commit = accs[0] / (double)NTOT;
        const double ent = accs[1] / (double)NTOT;
        out[COMMIT_OFF] = (float)(0.1 * 1.25 * commit);  // COMMIT_MULT * (1 + BETA)
        out[ENT_OFF] = (float)(0.1 * (ent - me));        // ENT_MULT
    }
}

extern "C" void kernel_launch(void* const* d_in, const int* in_sizes, int n_in,
                              void* d_out, int out_size, void* d_ws, size_t ws_size,
                              hipStream_t stream) {
    const float* z = (const float*)d_in[0];
    float* out = (float*)d_out;
    float* part = (float*)d_ws;

    lfq_main<<<NBLK, THREADS, 0, stream>>>(z, out, part);
    lfq_final<<<1, NBLK, 0, stream>>>(part, out);
}